// Round 6
// baseline (182.166 us; speedup 1.0000x reference)
//
#include <hip/hip_runtime.h>
#include <hip/hip_bf16.h>
#include <stdint.h>

typedef short short8 __attribute__((ext_vector_type(8)));
typedef float floatx4 __attribute__((ext_vector_type(4)));

#define NN 100000   // nodes (= 3125 * 32)
#define NE 800000   // edges
#define KF 128      // in_feat
#define PC 256      // P cols: [0:128)=P1 (src half, NO bias), [128:256)=P2 (dst half)
#define NTILES 3125 // node tiles of 32
#define NODEGRID 512

// pack 2 f32 -> packed bf16 dword (RNE via hw cvt)
__device__ __forceinline__ unsigned pk2(float x, float y) {
  union { __hip_bfloat162 h; unsigned u; } c;
  c.h = __float22bfloat162_rn(float2{x, y});
  return c.u;
}
__device__ __forceinline__ short8 cvt8(float4 a, float4 b) {
  union { short8 s; unsigned u[4]; } r;
  r.u[0] = pk2(a.x, a.y); r.u[1] = pk2(a.z, a.w);
  r.u[2] = pk2(b.x, b.y); r.u[3] = pk2(b.z, b.w);
  return r.s;
}
__device__ __forceinline__ float bfl(unsigned u) {
  union { unsigned u; float f; } c; c.u = u << 16; return c.f;
}
__device__ __forceinline__ float bfh(unsigned u) {
  union { unsigned u; float f; } c; c.u = u & 0xFFFF0000u; return c.f;
}

// ---------------------------------------------------------------------------
// Kernel 1 (streaming, ZERO LDS, ZERO barriers):
//   P[n][h*128+j] = sum_k feature[n][k] * W1[j][h*128+k]     (bias deferred)
// Wave w: half h=w>>1, nodes (w&1)*16. A operand = persistent W frags
// (8 jg x 4 kc short8 = 128 VGPRs, loaded once per block from L2-resident W1).
// B operand = feature frags loaded per tile straight from global (128 B
// contiguous per node). C frag: lane holds 4 CONSECUTIVE features of node
// m16 -> one packed 8 B store, natural P layout. Next-tile loads prefetched
// before the MFMAs.
// ---------------------------------------------------------------------------
extern "C" __global__ void __launch_bounds__(256, 2)
node_proj_kernel(const float* __restrict__ feature,
                 const float* __restrict__ W1,
                 unsigned short* __restrict__ P)
{
  const int t    = threadIdx.x;
  const int w    = t >> 6;
  const int lane = t & 63;
  const int m16  = lane & 15;
  const int quad = lane >> 4;
  const int h       = w >> 1;          // feature half
  const int nodeOff = (w & 1) * 16;    // node sub-tile

  // ---- persistent W A-frags: W1[jg*16+m16][h*128 + kc*32 + quad*8 + 0..7] ----
  short8 wfrag[8][4];
  #pragma unroll
  for (int jg = 0; jg < 8; ++jg)
    #pragma unroll
    for (int kc = 0; kc < 4; ++kc) {
      const float* wp = W1 + (jg * 16 + m16) * 256 + h * 128 + kc * 32 + quad * 8;
      wfrag[jg][kc] = cvt8(((const float4*)wp)[0], ((const float4*)wp)[1]);
    }

  int tile = blockIdx.x;
  // raw feature floats for current tile
  float4 raw[4][2];
  {
    const float* fp = feature + (size_t)(tile * 32 + nodeOff + m16) * KF + quad * 8;
    #pragma unroll
    for (int kc = 0; kc < 4; ++kc) {
      raw[kc][0] = ((const float4*)(fp + kc * 32))[0];
      raw[kc][1] = ((const float4*)(fp + kc * 32))[1];
    }
  }

  for (; tile < NTILES; tile += NODEGRID) {
    const int node = tile * 32 + nodeOff + m16;

    // convert current raw -> B frags (frees raw for prefetch)
    short8 nfrag[4];
    #pragma unroll
    for (int kc = 0; kc < 4; ++kc)
      nfrag[kc] = cvt8(raw[kc][0], raw[kc][1]);

    // prefetch next tile's raw floats (overlaps with MFMAs below)
    const int ntile = tile + NODEGRID;
    if (ntile < NTILES) {
      const float* fp = feature + (size_t)(ntile * 32 + nodeOff + m16) * KF + quad * 8;
      #pragma unroll
      for (int kc = 0; kc < 4; ++kc) {
        raw[kc][0] = ((const float4*)(fp + kc * 32))[0];
        raw[kc][1] = ((const float4*)(fp + kc * 32))[1];
      }
    }

    floatx4 acc[8];
    #pragma unroll
    for (int jg = 0; jg < 8; ++jg) acc[jg] = (floatx4){0.f, 0.f, 0.f, 0.f};

    #pragma unroll
    for (int kc = 0; kc < 4; ++kc)
      #pragma unroll
      for (int jg = 0; jg < 8; ++jg)
        acc[jg] = __builtin_amdgcn_mfma_f32_16x16x32_bf16(
            wfrag[jg][kc], nfrag[kc], acc[jg], 0, 0, 0);

    // C: col=m16 (node), row=quad*4+r (feature j = jg*16+quad*4+r).
    // Lane's 4 accs are 4 consecutive features of one node -> one 8 B store.
    unsigned short* pp = P + (size_t)node * PC + h * 128 + quad * 4;
    #pragma unroll
    for (int jg = 0; jg < 8; ++jg) {
      const unsigned lo = pk2(acc[jg][0], acc[jg][1]);
      const unsigned hi = pk2(acc[jg][2], acc[jg][3]);
      *(uint2*)(pp + jg * 16) = make_uint2(lo, hi);
    }
  }
}

// ---------------------------------------------------------------------------
// Kernel 2: out[e] = b2 + sum_j relu(P1[src][j] + P2[dst][j] + b1[j]) * W2[j]
// 16 lanes/edge (contiguous 256 B per edge-half), 4 edges/thread, bias b1
// applied here (preloaded, 8 VGPRs). lane0 stores a coalesced float4.
// ---------------------------------------------------------------------------
__device__ __forceinline__ float dot8(uint4 u1, uint4 u2, float4 wA, float4 wB,
                                      float4 bA, float4 bB) {
  float a = 0.f;
  a += fmaxf(bfl(u1.x) + bfl(u2.x) + bA.x, 0.f) * wA.x;
  a += fmaxf(bfh(u1.x) + bfh(u2.x) + bA.y, 0.f) * wA.y;
  a += fmaxf(bfl(u1.y) + bfl(u2.y) + bA.z, 0.f) * wA.z;
  a += fmaxf(bfh(u1.y) + bfh(u2.y) + bA.w, 0.f) * wA.w;
  a += fmaxf(bfl(u1.z) + bfl(u2.z) + bB.x, 0.f) * wB.x;
  a += fmaxf(bfh(u1.z) + bfh(u2.z) + bB.y, 0.f) * wB.y;
  a += fmaxf(bfl(u1.w) + bfl(u2.w) + bB.z, 0.f) * wB.z;
  a += fmaxf(bfh(u1.w) + bfh(u2.w) + bB.w, 0.f) * wB.w;
  return a;
}

extern "C" __global__ void __launch_bounds__(256)
edge_score_kernel(const unsigned short* __restrict__ P,
                  const int* __restrict__ src,
                  const int* __restrict__ dst,
                  const float* __restrict__ b1,
                  const float* __restrict__ W2,
                  const float* __restrict__ b2,
                  float* __restrict__ out)
{
  const int t    = threadIdx.x;
  const int lane = t & 15;
  const int g    = t >> 4;
  const int e0   = blockIdx.x * 64 + g * 4;

  const int s0 = src[e0],     d0 = dst[e0];
  const int s1 = src[e0 + 1], d1 = dst[e0 + 1];
  const int s2 = src[e0 + 2], d2 = dst[e0 + 2];
  const int s3 = src[e0 + 3], d3 = dst[e0 + 3];

  const size_t lo = (size_t)(lane * 8);
  const uint4 a0  = *(const uint4*)(P + (size_t)s0 * PC + lo);
  const uint4 b0  = *(const uint4*)(P + (size_t)d0 * PC + 128 + lo);
  const uint4 a1  = *(const uint4*)(P + (size_t)s1 * PC + lo);
  const uint4 b1v = *(const uint4*)(P + (size_t)d1 * PC + 128 + lo);
  const uint4 a2  = *(const uint4*)(P + (size_t)s2 * PC + lo);
  const uint4 b2v = *(const uint4*)(P + (size_t)d2 * PC + 128 + lo);
  const uint4 a3  = *(const uint4*)(P + (size_t)s3 * PC + lo);
  const uint4 b3v = *(const uint4*)(P + (size_t)d3 * PC + 128 + lo);

  const float4 wA = *(const float4*)(W2 + lane * 8);
  const float4 wB = *(const float4*)(W2 + lane * 8 + 4);
  const float4 bA = *(const float4*)(b1 + lane * 8);
  const float4 bB = *(const float4*)(b1 + lane * 8 + 4);

  float r0 = dot8(a0, b0,  wA, wB, bA, bB);
  float r1 = dot8(a1, b1v, wA, wB, bA, bB);
  float r2 = dot8(a2, b2v, wA, wB, bA, bB);
  float r3 = dot8(a3, b3v, wA, wB, bA, bB);

  #pragma unroll
  for (int s = 8; s >= 1; s >>= 1) {
    r0 += __shfl_xor(r0, s);
    r1 += __shfl_xor(r1, s);
    r2 += __shfl_xor(r2, s);
    r3 += __shfl_xor(r3, s);
  }

  if (lane == 0) {
    const float bb = b2[0];
    *(float4*)(out + e0) = make_float4(r0 + bb, r1 + bb, r2 + bb, r3 + bb);
  }
}

extern "C" void kernel_launch(void* const* d_in, const int* in_sizes, int n_in,
                              void* d_out, int out_size, void* d_ws, size_t ws_size,
                              hipStream_t stream)
{
  const float* feature = (const float*)d_in[0];
  const int*   src     = (const int*)d_in[1];
  const int*   dst     = (const int*)d_in[2];
  const float* W1      = (const float*)d_in[3];
  const float* b1      = (const float*)d_in[4];
  const float* W2      = (const float*)d_in[5];
  const float* b2      = (const float*)d_in[6];
  float* out = (float*)d_out;
  unsigned short* P = (unsigned short*)d_ws;  // [NN][256] bf16, 51.2 MB

  node_proj_kernel<<<NODEGRID, 256, 0, stream>>>(feature, W1, P);
  edge_score_kernel<<<NE / 64, 256, 0, stream>>>(P, src, dst, b1, W2, b2, out);
}